// Round 1
// baseline (1098.276 us; speedup 1.0000x reference)
//
#include <hip/hip_runtime.h>
#include <math.h>

#define PI2 6.283185307179586f

// B=32, H=128, W=128, C=128; hm modes 32 (rows 0..15,112..127), k modes 17
// Layouts (float2 = complex):
//  kout0/kin0: [32][128][2][64]; kout1/kin1: [17][128][2][64]
//  S0: [32][128][128]{d0,d1} as float4   S1: [17][128][128] float4
//  Xw/Q: [32][128][17][128] f2   Xf/Y: [32][32][17][128] f2

// ---------------- S build: S[s,i,j,d] = sum_r ko[s,i,d,r]*ki[s,j,d,r] -------
__global__ __launch_bounds__(128) void k_S(
    const float2* __restrict__ ko0, const float2* __restrict__ ki0,
    const float2* __restrict__ ko1, const float2* __restrict__ ki1,
    float4* __restrict__ S0, float4* __restrict__ S1) {
  int bid = blockIdx.x;
  int s = bid >> 7;      // 0..48
  int i = bid & 127;
  int j = threadIdx.x;   // 128 threads
  const float2* ko; const float2* ki; float4* S; int si;
  if (s < 32) { ko = ko0; ki = ki0; S = S0; si = s; }
  else        { ko = ko1; ki = ki1; S = S1; si = s - 32; }
  __shared__ float2 koS[2][64];
  koS[j >> 6][j & 63] = ko[(si * 128 + i) * 128 + j];
  __syncthreads();
  const float2* kirow = ki + (si * 128 + j) * 128;
  float2 acc[2];
#pragma unroll
  for (int d = 0; d < 2; d++) {
    float2 a2 = make_float2(0.f, 0.f);
    for (int r = 0; r < 64; r++) {
      float2 a = koS[d][r];
      float2 b = kirow[d * 64 + r];
      a2.x += a.x * b.x - a.y * b.y;
      a2.y += a.x * b.y + a.y * b.x;
    }
    acc[d] = a2;
  }
  S[(si * 128 + i) * 128 + j] = make_float4(acc[0].x, acc[0].y, acc[1].x, acc[1].y);
}

// ---------------- F1: Xw[b,y,k,c] = sc * sum_x X[b,y,x,c] e^{-i 2pi kx/128} -
// 4 y-rows per block (register-blocked); half-block kg=0 does k=0..8, kg=1 k=9..16.
// Each broadcast twiddle ds_read now feeds 4 rows (8 FMAs) instead of 2.
__global__ __launch_bounds__(256) void k_F1(
    const float* __restrict__ X, float2* __restrict__ Xw) {
  __shared__ float2 tw[128];
  int t = threadIdx.x;
  if (t < 128) { float s, c; __sincosf(PI2 * t / 128.f, &s, &c); tw[t] = make_float2(c, s); }
  __syncthreads();
  const char* twc = (const char*)tw;
  int c = t & 127, kg = t >> 7;
  int b = blockIdx.x >> 5;
  int y0 = (blockIdx.x & 31) * 4;
  const float* xr = X + ((size_t)(b * 128 + y0) * 128) * 128 + c;
  float2 a[4][9];
#pragma unroll
  for (int r = 0; r < 4; r++)
#pragma unroll
    for (int kk = 0; kk < 9; kk++) a[r][kk] = make_float2(0.f, 0.f);
  int kb8 = kg * 9 * 8;
  for (int x = 0; x < 128; x++) {
    float v0 = xr[x * 128];
    float v1 = xr[16384 + x * 128];
    float v2 = xr[32768 + x * 128];
    float v3 = xr[49152 + x * 128];
#pragma unroll
    for (int kk = 0; kk < 9; kk++) {
      int ob = ((kb8 + kk * 8) * x) & 1016;   // ((k*x)&127)*8
      float2 w = *(const float2*)(twc + ob);
      a[0][kk].x += v0 * w.x; a[0][kk].y -= v0 * w.y;
      a[1][kk].x += v1 * w.x; a[1][kk].y -= v1 * w.y;
      a[2][kk].x += v2 * w.x; a[2][kk].y -= v2 * w.y;
      a[3][kk].x += v3 * w.x; a[3][kk].y -= v3 * w.y;
    }
  }
  const float sc = 1.f / 16384.f;
  float2* o0 = Xw + ((size_t)(b * 128 + y0) * 17) * 128 + c;
#pragma unroll
  for (int r = 0; r < 4; r++) {
#pragma unroll
    for (int kk = 0; kk < 9; kk++) {
      int k = kg * 9 + kk;
      if (k < 17)
        o0[r * 2176 + k * 128] = make_float2(a[r][kk].x * sc, a[r][kk].y * sc);
    }
  }
}

// ---------------- F2: Xf[b,hm,k,c] = sum_y Xw[b,y,k,c] e^{-i 2pi h y/128} ---
// half-block hh handles hm = hh*16 .. hh*16+15; each thread loops all 128 y.
__global__ __launch_bounds__(256) void k_F2(
    const float2* __restrict__ Xw, float2* __restrict__ Xf) {
  __shared__ float2 tw[128];
  int t = threadIdx.x;
  if (t < 128) { float s, c; __sincosf(PI2 * t / 128.f, &s, &c); tw[t] = make_float2(c, s); }
  __syncthreads();
  const char* twc = (const char*)tw;
  int b = blockIdx.x / 17, k = blockIdx.x - b * 17;
  int c = t & 127, hh = t >> 7;
  float2 acc[16];
#pragma unroll
  for (int q = 0; q < 16; q++) acc[q] = make_float2(0.f, 0.f);
  int hb8 = hh ? 112 * 8 : 0;  // h = hm (hm<16) or hm+96; hm = hh*16+q
  const float2* xp = Xw + ((size_t)(b * 128) * 17 + k) * 128 + c;
  for (int y = 0; y < 128; y++) {
    float2 xv = xp[(size_t)y * 2176];
#pragma unroll
    for (int q = 0; q < 16; q++) {
      int ob = ((hb8 + q * 8) * y) & 1016;
      float2 w = *(const float2*)(twc + ob);
      acc[q].x += xv.x * w.x + xv.y * w.y;
      acc[q].y += xv.y * w.x - xv.x * w.y;
    }
  }
  float2* op = Xf + ((size_t)(b * 32 + hh * 16) * 17 + k) * 128 + c;
#pragma unroll
  for (int q = 0; q < 16; q++) op[(size_t)q * 2176] = acc[q];
}

// ---------------- spec (fused K): Y[b,m,i] = sum_j K[m,i,j] Xf[b,m,j] -------
// K[m,i,j] = sum_d S0[hm,i,j,d]*S1[w,i,j,d], computed in the staging step.
__global__ __launch_bounds__(256) void k_spec(
    const float4* __restrict__ S0, const float4* __restrict__ S1,
    const float2* __restrict__ Xf, float2* __restrict__ Y) {
  __shared__ float2 Xs[32][128];
  __shared__ float2 Ks[16][129];
  int m = blockIdx.x;
  int hm = m / 17, w = m - hm * 17;
  int t = threadIdx.x;
  for (int q = t; q < 32 * 128; q += 256) {
    int b = q >> 7, j = q & 127;
    Xs[b][j] = Xf[((size_t)(b * 32 + hm) * 17 + w) * 128 + j];
  }
  const float4* s0p = S0 + (size_t)hm * 16384;
  const float4* s1p = S1 + (size_t)w * 16384;
  int i = t & 127, bh = t >> 7;
  float2 acc[16];
#pragma unroll
  for (int bb = 0; bb < 16; bb++) acc[bb] = make_float2(0.f, 0.f);
  for (int jt = 0; jt < 128; jt += 16) {
    __syncthreads();
    for (int q = t; q < 16 * 128; q += 256) {
      int ii = q >> 4, jj = q & 15;
      float4 a = s0p[ii * 128 + jt + jj];
      float4 b4 = s1p[ii * 128 + jt + jj];
      Ks[jj][ii] = make_float2(a.x * b4.x - a.y * b4.y + a.z * b4.z - a.w * b4.w,
                               a.x * b4.y + a.y * b4.x + a.z * b4.w + a.w * b4.z);
    }
    __syncthreads();
#pragma unroll 4
    for (int jj = 0; jj < 16; jj++) {
      float2 kv = Ks[jj][i];
#pragma unroll
      for (int bb = 0; bb < 16; bb++) {
        float2 xv = Xs[bh * 16 + bb][jt + jj];
        acc[bb].x += kv.x * xv.x - kv.y * xv.y;
        acc[bb].y += kv.x * xv.y + kv.y * xv.x;
      }
    }
  }
#pragma unroll
  for (int bb = 0; bb < 16; bb++) {
    int b = bh * 16 + bb;
    Y[((size_t)(b * 32 + hm) * 17 + w) * 128 + i] = acc[bb];
  }
}

// ---------------- I1: Q[b,y,k,o] = sum_hm Y[b,hm,k,o] e^{+i 2pi h y/128} ----
// Y values held in 32 complex registers per thread.
__global__ __launch_bounds__(256) void k_I1(
    const float2* __restrict__ Y, float2* __restrict__ Q) {
  __shared__ float2 tw[128];
  int t = threadIdx.x;
  if (t < 128) { float s, c; __sincosf(PI2 * t / 128.f, &s, &c); tw[t] = make_float2(c, s); }
  __syncthreads();
  const char* twc = (const char*)tw;
  int b = blockIdx.x / 17, k = blockIdx.x - b * 17;
  int o = t & 127, yh = t >> 7;
  float2 v[32];
#pragma unroll
  for (int hm = 0; hm < 32; hm++)
    v[hm] = Y[((size_t)(b * 32 + hm) * 17 + k) * 128 + o];
  float2* qp = Q + ((size_t)(b * 128) * 17 + k) * 128 + o;
  for (int yy = 0; yy < 64; yy++) {
    int y = yh * 64 + yy;
    float2 a = make_float2(0.f, 0.f);
#pragma unroll
    for (int hm = 0; hm < 32; hm++) {
      const int h8 = (hm < 16 ? hm : hm + 96) * 8;
      int ob = (h8 * y) & 1016;
      float2 w = *(const float2*)(twc + ob);
      a.x += v[hm].x * w.x - v[hm].y * w.y;
      a.y += v[hm].x * w.y + v[hm].y * w.x;
    }
    qp[(size_t)y * 2176] = a;
  }
}

// ---------------- I2: out[b,y,x,o] = sum_k wk Re(Q[b,y,k,o] e^{+i 2pi kx/128})
// 4 y-rows per block (register-blocked); Q held in 4x17 complex registers
// (weight folded in). Each broadcast twiddle ds_read feeds 4 rows (8 FMAs).
__global__ __launch_bounds__(256) void k_I2(
    const float2* __restrict__ Q, float* __restrict__ out) {
  __shared__ float2 tw[128];
  int t = threadIdx.x;
  if (t < 128) { float s, c; __sincosf(PI2 * t / 128.f, &s, &c); tw[t] = make_float2(c, s); }
  __syncthreads();
  const char* twc = (const char*)tw;
  int b = blockIdx.x >> 5;
  int y0 = (blockIdx.x & 31) * 4;
  int o = t & 127, xh = t >> 7;
  const float2* qp = Q + ((size_t)(b * 128 + y0) * 17) * 128 + o;
  float2 q[4][17];
#pragma unroll
  for (int r = 0; r < 4; r++) {
#pragma unroll
    for (int k = 0; k < 17; k++) {
      float wgt = (k == 0) ? 1.f : 2.f;
      float2 v = qp[r * 2176 + k * 128];
      q[r][k] = make_float2(v.x * wgt, v.y * wgt);
    }
  }
  float* op = out + ((size_t)(b * 128 + y0) * 128) * 128 + o;
  for (int xx = 0; xx < 64; xx++) {
    int x = xh * 64 + xx;
    float s0 = 0.f, s1 = 0.f, s2 = 0.f, s3 = 0.f;
#pragma unroll
    for (int k = 0; k < 17; k++) {
      int ob = (k * 8 * x) & 1016;
      float2 w = *(const float2*)(twc + ob);
      s0 += q[0][k].x * w.x - q[0][k].y * w.y;
      s1 += q[1][k].x * w.x - q[1][k].y * w.y;
      s2 += q[2][k].x * w.x - q[2][k].y * w.y;
      s3 += q[3][k].x * w.x - q[3][k].y * w.y;
    }
    op[x * 128] = s0;
    op[16384 + x * 128] = s1;
    op[32768 + x * 128] = s2;
    op[49152 + x * 128] = s3;
  }
}

extern "C" void kernel_launch(void* const* d_in, const int* in_sizes, int n_in,
                              void* d_out, int out_size, void* d_ws, size_t ws_size,
                              hipStream_t stream) {
  (void)in_sizes; (void)n_in; (void)out_size;
  const float*  X     = (const float*)d_in[0];
  const float2* kout0 = (const float2*)d_in[1];
  const float2* kin0  = (const float2*)d_in[2];
  const float2* kout1 = (const float2*)d_in[3];
  const float2* kin1  = (const float2*)d_in[4];
  float* out = (float*)d_out;

  // Workspace (float2 units): A (Xw, reused as Q) | S0 | S1 | Xf | Y  = ~120 MB
  float2* ws = (float2*)d_ws;
  const size_t NA = 8912896;                 // 32*128*17*128
  float2* A  = ws;
  float2* S0 = ws + NA;                      // 1,048,576 f2 (as float4: 524,288)
  float2* S1 = S0 + 1048576;                 //   557,056 f2
  float2* Xf = S1 + 557056;                  // 2,228,224 f2
  float2* Yk = Xf + 2228224;                 // 2,228,224 f2
  const size_t need = (NA + 1048576 + 557056 + 2 * 2228224) * sizeof(float2);
  if (ws_size < need) return;

  k_S   <<<49 * 128, 128, 0, stream>>>(kout0, kin0, kout1, kin1,
                                       (float4*)S0, (float4*)S1);
  k_F1  <<<32 * 32, 256, 0, stream>>>(X, A);
  k_F2  <<<32 * 17, 256, 0, stream>>>(A, Xf);
  k_spec<<<544, 256, 0, stream>>>((const float4*)S0, (const float4*)S1, Xf, Yk);
  k_I1  <<<32 * 17, 256, 0, stream>>>(Yk, A);
  k_I2  <<<32 * 32, 256, 0, stream>>>(A, out);
}